// Round 1
// baseline (774.393 us; speedup 1.0000x reference)
//
#include <hip/hip_runtime.h>

// ---------------------------------------------------------------------------
// GQA with algebraic collapse:
//   x_embed = x*fe_w + (fe_b+pos_emb)  (affine in scalar x[b,s])
//   K[b,s,j] = x[b,s]*kc[j] + kp[s,j];  V likewise (vc, vp)
//   score2[b,row,s] = x[b,s]*qa[row] + qb[row,s]   (log2e/SCALE folded in)
//   ctx = inv * ( vc[g,d]*sum(e*x) + sum(e*vp[s,g,d]) )
// row = (g*4+r)*8+q = h*8+q, h = row>>3, q = row&7, g = row>>5
// ---------------------------------------------------------------------------

#define WS_QB 0        // 64*1024 floats : qb[row][s]
#define WS_VPT 65536   // 16*1024 floats : vp_t[j][s]  (j = g*8+d)
#define WS_QA 81920    // 64 floats
#define WS_VC 81984    // 16 floats

constexpr float CEXP = (float)(1.4426950408889634 / 2.8284271247461903); // log2(e)/sqrt(8)

__device__ __forceinline__ float wred_max(float v) {
#pragma unroll
  for (int off = 32; off; off >>= 1) v = fmaxf(v, __shfl_xor(v, off, 64));
  return v;
}
__device__ __forceinline__ float wred_sum(float v) {
#pragma unroll
  for (int off = 32; off; off >>= 1) v += __shfl_xor(v, off, 64);
  return v;
}

// ---- kernel A: kc, vc, qa ---------------------------------------------------
__global__ void precompute_small(const float* __restrict__ queries,
                                 const float* __restrict__ fe_w,
                                 const float* __restrict__ k_w,
                                 const float* __restrict__ v_w,
                                 float* __restrict__ ws) {
  __shared__ float kc[16];
  int t = threadIdx.x;  // 64 threads
  if (t < 32) {
    int j = t & 15;
    const float* wm = (t < 16) ? k_w : v_w;
    float s = 0.f;
#pragma unroll 8
    for (int d = 0; d < 64; ++d) s += fe_w[d] * wm[d * 16 + j];
    if (t < 16) kc[j] = s;
    else ws[WS_VC + j] = s;
  }
  __syncthreads();
  int row = t, g = row >> 5, r = (row >> 3) & 3, q = row & 7;
  float s = 0.f;
#pragma unroll
  for (int hd = 0; hd < 8; ++hd)
    s += queries[q * 64 + g * 32 + r * 8 + hd] * kc[g * 8 + hd];
  ws[WS_QA + row] = s * CEXP;
}

// ---- kernel B: per-position tables kp -> qb, vp_t --------------------------
__global__ void precompute_tables(const float* __restrict__ queries,
                                  const float* __restrict__ fe_b,
                                  const float* __restrict__ pos_emb,
                                  const float* __restrict__ k_w,
                                  const float* __restrict__ k_b,
                                  const float* __restrict__ v_w,
                                  const float* __restrict__ v_b,
                                  float* __restrict__ ws) {
  __shared__ float emb[64];
  __shared__ float kp[16];
  int sp = blockIdx.x, t = threadIdx.x;  // 1024 blocks x 64 threads
  emb[t] = fe_b[t] + pos_emb[sp * 64 + t];
  __syncthreads();
  if (t < 32) {
    int j = t & 15;
    const float* wm = (t < 16) ? k_w : v_w;
    const float* bv = (t < 16) ? k_b : v_b;
    float s = bv[j];
#pragma unroll 8
    for (int d = 0; d < 64; ++d) s += emb[d] * wm[d * 16 + j];
    if (t < 16) kp[j] = s;
    else ws[WS_VPT + j * 1024 + sp] = s;
  }
  __syncthreads();
  int row = t, g = row >> 5, r = (row >> 3) & 3, q = row & 7;
  float s = 0.f;
#pragma unroll
  for (int hd = 0; hd < 8; ++hd)
    s += queries[q * 64 + g * 32 + r * 8 + hd] * kp[g * 8 + hd];
  ws[WS_QB + row * 1024 + sp] = s * CEXP;
}

// ---- kernel C: main — scores, softmax, attn write, PV accumulation ---------
// grid 2048 = (b, g-half); block 256 = 4 waves; wave owns 8 rows.
__launch_bounds__(256, 3)
__global__ void gqa_main(const float* __restrict__ x,
                         const float* __restrict__ ws,
                         float* __restrict__ dout) {
  int b = blockIdx.x >> 1;
  int g = blockIdx.x & 1;
  int t = threadIdx.x;
  int w = t >> 6, lane = t & 63;
  __shared__ float4 xs[256];
  xs[t] = ((const float4*)(x + b * 1024))[t];
  __syncthreads();

  const float4* qb4 = (const float4*)(ws + WS_QB);   // [64][256]
  const float4* vp4 = (const float4*)(ws + WS_VPT);  // [16][256]
  const float* qa = ws + WS_QA;
  const float* vc = ws + WS_VC;

  int row0 = g * 32 + w * 8;
  float qa_r[8], m_r[8], inv_r[8];
#pragma unroll
  for (int rr = 0; rr < 8; ++rr) qa_r[rr] = qa[row0 + rr];

  // ---- pass A: per-row max & sum (exp2 domain) ----
#pragma unroll
  for (int rr = 0; rr < 8; ++rr) {
    int row = row0 + rr;
    float4 sc[4];
#pragma unroll
    for (int i = 0; i < 4; ++i) {
      float4 xv = xs[i * 64 + lane];
      float4 qv = qb4[row * 256 + i * 64 + lane];
      sc[i].x = fmaf(xv.x, qa_r[rr], qv.x);
      sc[i].y = fmaf(xv.y, qa_r[rr], qv.y);
      sc[i].z = fmaf(xv.z, qa_r[rr], qv.z);
      sc[i].w = fmaf(xv.w, qa_r[rr], qv.w);
    }
    float m0 = fmaxf(fmaxf(sc[0].x, sc[0].y), fmaxf(sc[0].z, sc[0].w));
    float m1 = fmaxf(fmaxf(sc[1].x, sc[1].y), fmaxf(sc[1].z, sc[1].w));
    float m2 = fmaxf(fmaxf(sc[2].x, sc[2].y), fmaxf(sc[2].z, sc[2].w));
    float m3 = fmaxf(fmaxf(sc[3].x, sc[3].y), fmaxf(sc[3].z, sc[3].w));
    float m = wred_max(fmaxf(fmaxf(m0, m1), fmaxf(m2, m3)));
    float sum = 0.f;
#pragma unroll
    for (int i = 0; i < 4; ++i) {
      sum += exp2f(sc[i].x - m);
      sum += exp2f(sc[i].y - m);
      sum += exp2f(sc[i].z - m);
      sum += exp2f(sc[i].w - m);
    }
    sum = wred_sum(sum);
    m_r[rr] = m;
    inv_r[rr] = 1.f / sum;
  }

  // ---- pass B: recompute e, write attn, accumulate PV ----
  float accx[8];
  float acc[8][8];
#pragma unroll
  for (int rr = 0; rr < 8; ++rr) {
    accx[rr] = 0.f;
#pragma unroll
    for (int d = 0; d < 8; ++d) acc[rr][d] = 0.f;
  }

  float* attn = dout + 524288 + (size_t)b * 65536;

#pragma unroll
  for (int i = 0; i < 4; ++i) {
    float4 xv = xs[i * 64 + lane];
    float4 vv[8];
#pragma unroll
    for (int d = 0; d < 8; ++d)
      vv[d] = vp4[(g * 8 + d) * 256 + i * 64 + lane];
#pragma unroll
    for (int rr = 0; rr < 8; ++rr) {
      int row = row0 + rr;
      float4 qv = qb4[row * 256 + i * 64 + lane];
      float4 e;
      e.x = exp2f(fmaf(xv.x, qa_r[rr], qv.x) - m_r[rr]);
      e.y = exp2f(fmaf(xv.y, qa_r[rr], qv.y) - m_r[rr]);
      e.z = exp2f(fmaf(xv.z, qa_r[rr], qv.z) - m_r[rr]);
      e.w = exp2f(fmaf(xv.w, qa_r[rr], qv.w) - m_r[rr]);
      float iv = inv_r[rr];
      float4 av;
      av.x = e.x * iv; av.y = e.y * iv; av.z = e.z * iv; av.w = e.w * iv;
      *((float4*)(attn + row * 1024 + i * 256 + lane * 4)) = av;
      accx[rr] = fmaf(e.x, xv.x, accx[rr]);
      accx[rr] = fmaf(e.y, xv.y, accx[rr]);
      accx[rr] = fmaf(e.z, xv.z, accx[rr]);
      accx[rr] = fmaf(e.w, xv.w, accx[rr]);
#pragma unroll
      for (int d = 0; d < 8; ++d) {
        acc[rr][d] = fmaf(e.x, vv[d].x, acc[rr][d]);
        acc[rr][d] = fmaf(e.y, vv[d].y, acc[rr][d]);
        acc[rr][d] = fmaf(e.z, vv[d].z, acc[rr][d]);
        acc[rr][d] = fmaf(e.w, vv[d].w, acc[rr][d]);
      }
    }
  }

  // ---- reduce and write ctx into the out region (kernel D consumes it) ----
#pragma unroll
  for (int rr = 0; rr < 8; ++rr) {
    accx[rr] = wred_sum(accx[rr]);
#pragma unroll
    for (int d = 0; d < 8; ++d) acc[rr][d] = wred_sum(acc[rr][d]);
    if (lane == 0) {
      int row = row0 + rr, h = row >> 3, q = row & 7;
      float iv = inv_r[rr];
#pragma unroll
      for (int d = 0; d < 8; ++d)
        dout[b * 512 + q * 64 + h * 8 + d] =
            iv * fmaf(vc[g * 8 + d], accx[rr], acc[rr][d]);
    }
  }
}

// ---- kernel D: in-place output projection out = ctx @ o_w + o_b ------------
__global__ void oproj(const float* __restrict__ o_w,
                      const float* __restrict__ o_b,
                      float* __restrict__ dout) {
  __shared__ float cx[512];
  int b = blockIdx.x, t = threadIdx.x;  // 1024 blocks x 512 threads
  cx[t] = dout[b * 512 + t];
  __syncthreads();
  int q = t >> 6, e = t & 63;
  float s = o_b[e];
#pragma unroll
  for (int k = 0; k < 64; ++k)
    s = fmaf(cx[q * 64 + k], o_w[k * 64 + e], s);
  dout[b * 512 + t] = s;
}

extern "C" void kernel_launch(void* const* d_in, const int* in_sizes, int n_in,
                              void* d_out, int out_size, void* d_ws, size_t ws_size,
                              hipStream_t stream) {
  const float* x       = (const float*)d_in[0];
  const float* queries = (const float*)d_in[1];
  const float* fe_w    = (const float*)d_in[2];
  const float* fe_b    = (const float*)d_in[3];
  const float* pos_emb = (const float*)d_in[4];
  const float* k_w     = (const float*)d_in[5];
  const float* k_b     = (const float*)d_in[6];
  const float* v_w     = (const float*)d_in[7];
  const float* v_b     = (const float*)d_in[8];
  const float* o_w     = (const float*)d_in[9];
  const float* o_b     = (const float*)d_in[10];
  float* ws = (float*)d_ws;
  float* out = (float*)d_out;

  hipLaunchKernelGGL(precompute_small, dim3(1), dim3(64), 0, stream,
                     queries, fe_w, k_w, v_w, ws);
  hipLaunchKernelGGL(precompute_tables, dim3(1024), dim3(64), 0, stream,
                     queries, fe_b, pos_emb, k_w, k_b, v_w, v_b, ws);
  hipLaunchKernelGGL(gqa_main, dim3(2048), dim3(256), 0, stream, x, ws, out);
  hipLaunchKernelGGL(oproj, dim3(1024), dim3(512), 0, stream, o_w, o_b, out);
}

// Round 5
// 749.916 us; speedup vs baseline: 1.0326x; 1.0326x over previous
//
#include <hip/hip_runtime.h>

// ---------------------------------------------------------------------------
// GQA with algebraic collapse:
//   x_embed = x*fe_w + (fe_b+pos_emb)  (affine in scalar x[b,s])
//   K[b,s,j] = x[b,s]*kc[j] + kp[s,j];  V likewise (vc, vp)
//   score2[b,row,s] = x[b,s]*qa[row] + qb[row,s]   (log2e/SCALE folded in)
//   ctx = inv * ( vc[g,d]*sum(e*x) + sum(e*vp[s,g,d]) )
// row = (g*4+r)*8+q = h*8+q, h = row>>3, q = row&7, g = row>>5
//
// R1/R2 change: attn stores are NON-TEMPORAL (bypass L2) so the 268 MB write
// stream stops evicting the qb/vp tables from L2 (R0 profile: 495 MB fetch =
// table re-reads missing L2; 900 MB write = thrash churn). R2 fixes the
// builtin's type requirement via a native ext_vector_type(4) alias.
// R3/R4: identical resubmits (GPU acquisition timeouts — never ran).
// ---------------------------------------------------------------------------

typedef float floatx4 __attribute__((ext_vector_type(4)));

#define WS_QB 0        // 64*1024 floats : qb[row][s]
#define WS_VPT 65536   // 16*1024 floats : vp_t[j][s]  (j = g*8+d)
#define WS_QA 81920    // 64 floats
#define WS_VC 81984    // 16 floats

constexpr float CEXP = (float)(1.4426950408889634 / 2.8284271247461903); // log2(e)/sqrt(8)

__device__ __forceinline__ float wred_max(float v) {
#pragma unroll
  for (int off = 32; off; off >>= 1) v = fmaxf(v, __shfl_xor(v, off, 64));
  return v;
}
__device__ __forceinline__ float wred_sum(float v) {
#pragma unroll
  for (int off = 32; off; off >>= 1) v += __shfl_xor(v, off, 64);
  return v;
}

// ---- kernel A: kc, vc, qa ---------------------------------------------------
__global__ void precompute_small(const float* __restrict__ queries,
                                 const float* __restrict__ fe_w,
                                 const float* __restrict__ k_w,
                                 const float* __restrict__ v_w,
                                 float* __restrict__ ws) {
  __shared__ float kc[16];
  int t = threadIdx.x;  // 64 threads
  if (t < 32) {
    int j = t & 15;
    const float* wm = (t < 16) ? k_w : v_w;
    float s = 0.f;
#pragma unroll 8
    for (int d = 0; d < 64; ++d) s += fe_w[d] * wm[d * 16 + j];
    if (t < 16) kc[j] = s;
    else ws[WS_VC + j] = s;
  }
  __syncthreads();
  int row = t, g = row >> 5, r = (row >> 3) & 3, q = row & 7;
  float s = 0.f;
#pragma unroll
  for (int hd = 0; hd < 8; ++hd)
    s += queries[q * 64 + g * 32 + r * 8 + hd] * kc[g * 8 + hd];
  ws[WS_QA + row] = s * CEXP;
}

// ---- kernel B: per-position tables kp -> qb, vp_t --------------------------
__global__ void precompute_tables(const float* __restrict__ queries,
                                  const float* __restrict__ fe_b,
                                  const float* __restrict__ pos_emb,
                                  const float* __restrict__ k_w,
                                  const float* __restrict__ k_b,
                                  const float* __restrict__ v_w,
                                  const float* __restrict__ v_b,
                                  float* __restrict__ ws) {
  __shared__ float emb[64];
  __shared__ float kp[16];
  int sp = blockIdx.x, t = threadIdx.x;  // 1024 blocks x 64 threads
  emb[t] = fe_b[t] + pos_emb[sp * 64 + t];
  __syncthreads();
  if (t < 32) {
    int j = t & 15;
    const float* wm = (t < 16) ? k_w : v_w;
    const float* bv = (t < 16) ? k_b : v_b;
    float s = bv[j];
#pragma unroll 8
    for (int d = 0; d < 64; ++d) s += emb[d] * wm[d * 16 + j];
    if (t < 16) kp[j] = s;
    else ws[WS_VPT + j * 1024 + sp] = s;
  }
  __syncthreads();
  int row = t, g = row >> 5, r = (row >> 3) & 3, q = row & 7;
  float s = 0.f;
#pragma unroll
  for (int hd = 0; hd < 8; ++hd)
    s += queries[q * 64 + g * 32 + r * 8 + hd] * kp[g * 8 + hd];
  ws[WS_QB + row * 1024 + sp] = s * CEXP;
}

// ---- kernel C: main — scores, softmax, attn write, PV accumulation ---------
// grid 2048 = (b, g-half); block 256 = 4 waves; wave owns 8 rows.
__launch_bounds__(256, 3)
__global__ void gqa_main(const float* __restrict__ x,
                         const float* __restrict__ ws,
                         float* __restrict__ dout) {
  int b = blockIdx.x >> 1;
  int g = blockIdx.x & 1;
  int t = threadIdx.x;
  int w = t >> 6, lane = t & 63;
  __shared__ float4 xs[256];
  xs[t] = ((const float4*)(x + b * 1024))[t];
  __syncthreads();

  const float4* qb4 = (const float4*)(ws + WS_QB);   // [64][256]
  const float4* vp4 = (const float4*)(ws + WS_VPT);  // [16][256]
  const float* qa = ws + WS_QA;
  const float* vc = ws + WS_VC;

  int row0 = g * 32 + w * 8;
  float qa_r[8], m_r[8], inv_r[8];
#pragma unroll
  for (int rr = 0; rr < 8; ++rr) qa_r[rr] = qa[row0 + rr];

  // ---- pass A: per-row max & sum (exp2 domain) ----
#pragma unroll
  for (int rr = 0; rr < 8; ++rr) {
    int row = row0 + rr;
    float4 sc[4];
#pragma unroll
    for (int i = 0; i < 4; ++i) {
      float4 xv = xs[i * 64 + lane];
      float4 qv = qb4[row * 256 + i * 64 + lane];
      sc[i].x = fmaf(xv.x, qa_r[rr], qv.x);
      sc[i].y = fmaf(xv.y, qa_r[rr], qv.y);
      sc[i].z = fmaf(xv.z, qa_r[rr], qv.z);
      sc[i].w = fmaf(xv.w, qa_r[rr], qv.w);
    }
    float m0 = fmaxf(fmaxf(sc[0].x, sc[0].y), fmaxf(sc[0].z, sc[0].w));
    float m1 = fmaxf(fmaxf(sc[1].x, sc[1].y), fmaxf(sc[1].z, sc[1].w));
    float m2 = fmaxf(fmaxf(sc[2].x, sc[2].y), fmaxf(sc[2].z, sc[2].w));
    float m3 = fmaxf(fmaxf(sc[3].x, sc[3].y), fmaxf(sc[3].z, sc[3].w));
    float m = wred_max(fmaxf(fmaxf(m0, m1), fmaxf(m2, m3)));
    float sum = 0.f;
#pragma unroll
    for (int i = 0; i < 4; ++i) {
      sum += exp2f(sc[i].x - m);
      sum += exp2f(sc[i].y - m);
      sum += exp2f(sc[i].z - m);
      sum += exp2f(sc[i].w - m);
    }
    sum = wred_sum(sum);
    m_r[rr] = m;
    inv_r[rr] = 1.f / sum;
  }

  // ---- pass B: recompute e, write attn (non-temporal), accumulate PV ----
  float accx[8];
  float acc[8][8];
#pragma unroll
  for (int rr = 0; rr < 8; ++rr) {
    accx[rr] = 0.f;
#pragma unroll
    for (int d = 0; d < 8; ++d) acc[rr][d] = 0.f;
  }

  float* attn = dout + 524288 + (size_t)b * 65536;

#pragma unroll
  for (int i = 0; i < 4; ++i) {
    float4 xv = xs[i * 64 + lane];
    float4 vv[8];
#pragma unroll
    for (int d = 0; d < 8; ++d)
      vv[d] = vp4[(g * 8 + d) * 256 + i * 64 + lane];
#pragma unroll
    for (int rr = 0; rr < 8; ++rr) {
      int row = row0 + rr;
      float4 qv = qb4[row * 256 + i * 64 + lane];
      float4 e;
      e.x = exp2f(fmaf(xv.x, qa_r[rr], qv.x) - m_r[rr]);
      e.y = exp2f(fmaf(xv.y, qa_r[rr], qv.y) - m_r[rr]);
      e.z = exp2f(fmaf(xv.z, qa_r[rr], qv.z) - m_r[rr]);
      e.w = exp2f(fmaf(xv.w, qa_r[rr], qv.w) - m_r[rr]);
      float iv = inv_r[rr];
      floatx4 av;
      av.x = e.x * iv; av.y = e.y * iv; av.z = e.z * iv; av.w = e.w * iv;
      __builtin_nontemporal_store(av, (floatx4*)(attn + row * 1024 + i * 256 + lane * 4));
      accx[rr] = fmaf(e.x, xv.x, accx[rr]);
      accx[rr] = fmaf(e.y, xv.y, accx[rr]);
      accx[rr] = fmaf(e.z, xv.z, accx[rr]);
      accx[rr] = fmaf(e.w, xv.w, accx[rr]);
#pragma unroll
      for (int d = 0; d < 8; ++d) {
        acc[rr][d] = fmaf(e.x, vv[d].x, acc[rr][d]);
        acc[rr][d] = fmaf(e.y, vv[d].y, acc[rr][d]);
        acc[rr][d] = fmaf(e.z, vv[d].z, acc[rr][d]);
        acc[rr][d] = fmaf(e.w, vv[d].w, acc[rr][d]);
      }
    }
  }

  // ---- reduce and write ctx into the out region (kernel D consumes it) ----
#pragma unroll
  for (int rr = 0; rr < 8; ++rr) {
    accx[rr] = wred_sum(accx[rr]);
#pragma unroll
    for (int d = 0; d < 8; ++d) acc[rr][d] = wred_sum(acc[rr][d]);
    if (lane == 0) {
      int row = row0 + rr, h = row >> 3, q = row & 7;
      float iv = inv_r[rr];
#pragma unroll
      for (int d = 0; d < 8; ++d)
        dout[b * 512 + q * 64 + h * 8 + d] =
            iv * fmaf(vc[g * 8 + d], accx[rr], acc[rr][d]);
    }
  }
}

// ---- kernel D: in-place output projection out = ctx @ o_w + o_b ------------
__global__ void oproj(const float* __restrict__ o_w,
                      const float* __restrict__ o_b,
                      float* __restrict__ dout) {
  __shared__ float cx[512];
  int b = blockIdx.x, t = threadIdx.x;  // 1024 blocks x 512 threads
  cx[t] = dout[b * 512 + t];
  __syncthreads();
  int q = t >> 6, e = t & 63;
  float s = o_b[e];
#pragma unroll
  for (int k = 0; k < 64; ++k)
    s = fmaf(cx[q * 64 + k], o_w[k * 64 + e], s);
  dout[b * 512 + t] = s;
}

extern "C" void kernel_launch(void* const* d_in, const int* in_sizes, int n_in,
                              void* d_out, int out_size, void* d_ws, size_t ws_size,
                              hipStream_t stream) {
  const float* x       = (const float*)d_in[0];
  const float* queries = (const float*)d_in[1];
  const float* fe_w    = (const float*)d_in[2];
  const float* fe_b    = (const float*)d_in[3];
  const float* pos_emb = (const float*)d_in[4];
  const float* k_w     = (const float*)d_in[5];
  const float* k_b     = (const float*)d_in[6];
  const float* v_w     = (const float*)d_in[7];
  const float* v_b     = (const float*)d_in[8];
  const float* o_w     = (const float*)d_in[9];
  const float* o_b     = (const float*)d_in[10];
  float* ws = (float*)d_ws;
  float* out = (float*)d_out;

  hipLaunchKernelGGL(precompute_small, dim3(1), dim3(64), 0, stream,
                     queries, fe_w, k_w, v_w, ws);
  hipLaunchKernelGGL(precompute_tables, dim3(1024), dim3(64), 0, stream,
                     queries, fe_b, pos_emb, k_w, k_b, v_w, v_b, ws);
  hipLaunchKernelGGL(gqa_main, dim3(2048), dim3(256), 0, stream, x, ws, out);
  hipLaunchKernelGGL(oproj, dim3(1024), dim3(512), 0, stream, o_w, o_b, out);
}